// Round 6
// baseline (851.567 us; speedup 1.0000x reference)
//
#include <hip/hip_runtime.h>
#include <cstddef>

#define EPSF 1e-12f

constexpr int Bc = 16, Dc = 128, Lc = 4096, Kc = 4096;
constexpr int Nc = Bc * Lc;     // 65536
constexpr float TAU = 1e-4f;    // 2x split-bf16 err (~4e-5) + 8-bit pack err (~3e-5)
constexpr int RCAP = 32768;

typedef __attribute__((ext_vector_type(8))) short short8;
typedef __attribute__((ext_vector_type(4))) float f32x4;

__device__ __forceinline__ unsigned short f2bf(float f) {
    unsigned u = __float_as_uint(f);
    return (unsigned short)((u + 0x7fffu + ((u >> 16) & 1u)) >> 16);
}
__device__ __forceinline__ float bf2f(unsigned short u) {
    return __uint_as_float(((unsigned)u) << 16);
}

// ---------------------------------------------------------------------------
// Fused codebook prep: normalize -> cbn (f32) AND bf16-split MFMA-operand
// blob.  Block = one 16-code group (g): thread (r = code, c = 8-dim chunk).
// Blob layout (same as r5): group g -> 8 frags (kd x {hi,lo}) of 1024B;
// slot (q*16 + r)*16 holds dims (kd*4+q)*8..+7 of code r.
// ---------------------------------------------------------------------------
__global__ void k_prep(const float* __restrict__ emb, float* __restrict__ cbn,
                       char* __restrict__ blob, float* __restrict__ lacc,
                       int* __restrict__ rcnt) {
    const int g = blockIdx.x;
    const int t = threadIdx.x;
    const int r = t >> 4;            // code within group
    const int c = t & 15;            // 8-dim chunk
    const int k = g * 16 + r;
    const float* src = emb + (size_t)k * Dc + c * 8;
    float4 a = *(const float4*)src;
    float4 b = *(const float4*)(src + 4);
    float s = a.x * a.x + a.y * a.y + a.z * a.z + a.w * a.w
            + b.x * b.x + b.y * b.y + b.z * b.z + b.w * b.w;
    s += __shfl_xor(s, 1); s += __shfl_xor(s, 2);
    s += __shfl_xor(s, 4); s += __shfl_xor(s, 8);   // 16-lane group = one code
    float inv = 1.f / fmaxf(sqrtf(s), EPSF);
    a.x *= inv; a.y *= inv; a.z *= inv; a.w *= inv;
    b.x *= inv; b.y *= inv; b.z *= inv; b.w *= inv;
    *(float4*)(cbn + (size_t)k * Dc + c * 8)     = a;
    *(float4*)(cbn + (size_t)k * Dc + c * 8 + 4) = b;
    float v[8] = {a.x, a.y, a.z, a.w, b.x, b.y, b.z, b.w};
    short8 hh, ll;
    #pragma unroll
    for (int j = 0; j < 8; ++j) {
        unsigned short hb = f2bf(v[j]);
        hh[j] = (short)hb;
        ll[j] = (short)f2bf(v[j] - bf2f(hb));
    }
    char* base = blob + (size_t)g * 8192 + (size_t)((c >> 2) * 2) * 1024
               + (size_t)((c & 3) * 16 + r) * 16;
    *(short8*)base          = hh;
    *(short8*)(base + 1024) = ll;
    if (g == 0 && t == 0) { *lacc = 0.f; *rcnt = 0; }
}

// ---------------------------------------------------------------------------
// MFMA argmax.  Block = 256 thr / 4 waves = (2 rowsets x 2 codesets),
// 64 rows/block, grid 1024 = 4 independent blocks per CU (16 waves/CU).
// Per wave: 32 rows in A regs (rt=2), tile = 32 codes (16 per codeset),
// double-buffered 2x16KB LDS, all accesses lane-linear. 8-bit packed fold.
// Reg budget <=128 unified (A 64 + acc 8 + pf 16 + fold 16 + misc).
// ---------------------------------------------------------------------------
__global__ __launch_bounds__(256, 4)
void k_argmax(const float* __restrict__ x, const char* __restrict__ blob,
              float* __restrict__ invn, int* __restrict__ idx_out,
              float* __restrict__ lossacc, int* __restrict__ rcnt,
              int* __restrict__ rlist) {
    __shared__ __align__(16) char smem[33280];
    float* xt   = (float*)smem;              // [64][129] (preamble overlay)
    float* invl = (float*)(smem + 33024);    // [64]

    const int tid  = threadIdx.x;
    const int w    = tid >> 6;
    const int lane = tid & 63;
    const int m16  = lane & 15;
    const int quad = lane >> 4;
    const int rs   = w >> 1;      // rowset 0/1 (32 rows each)
    const int cs   = w & 1;       // codeset 0/1 (16 codes per tile)
    const int n0   = blockIdx.x * 64;
    const int bI   = n0 >> 12;
    const int l0   = n0 & (Lc - 1);
    const float* xb = x + (size_t)bI * Dc * Lc;

    // ---- tile-0 prefetch (lane-linear, 4KB/instr across the block) ----
    const char* pb = blob + tid * 16;
    int4 pf[4];
    #pragma unroll
    for (int j = 0; j < 4; ++j) pf[j] = *(const int4*)(pb + j * 4096);

    // ---- preamble: transpose+normalize 64 rows, build per-wave A frags ----
    short8 ah[2][4], al[2][4];
    #pragma unroll
    for (int j = 0; j < 8; ++j) {
        int fl = tid + j * 256;              // 0..2047
        int d = fl >> 4, lq = fl & 15;
        float4 v = *(const float4*)(xb + (size_t)d * Lc + l0 + lq * 4);
        xt[(lq * 4 + 0) * 129 + d] = v.x;
        xt[(lq * 4 + 1) * 129 + d] = v.y;
        xt[(lq * 4 + 2) * 129 + d] = v.z;
        xt[(lq * 4 + 3) * 129 + d] = v.w;
    }
    __syncthreads();
    {   // row norms, 4 threads/row
        int row = tid >> 2, q = tid & 3;
        float s = 0.f;
        #pragma unroll
        for (int j = 0; j < 32; ++j) { float t = xt[row * 129 + q * 32 + j]; s += t * t; }
        s += __shfl_xor(s, 1); s += __shfl_xor(s, 2);
        if (q == 0) {
            float inv = 1.f / fmaxf(sqrtf(s), EPSF);
            invl[row] = inv;
            invn[n0 + row] = inv;
        }
    }
    __syncthreads();
    #pragma unroll
    for (int rt = 0; rt < 2; ++rt) {
        int rl = rs * 32 + rt * 16 + m16;    // A layout: m = lane&15
        float inv = invl[rl];
        #pragma unroll
        for (int kd = 0; kd < 4; ++kd) {
            int dof = kd * 32 + quad * 8;    // k = quad*8 + j
            short8 hhv, llv;
            #pragma unroll
            for (int j = 0; j < 8; ++j) {
                float xn = xt[rl * 129 + dof + j] * inv;
                unsigned short hb = f2bf(xn);
                hhv[j] = (short)hb;
                llv[j] = (short)f2bf(xn - bf2f(hb));
            }
            ah[rt][kd] = hhv; al[rt][kd] = llv;
        }
    }
    __syncthreads();   // xt dead; double-buffer owns smem[0..32768)

    // ---- K loop: 128 tiles of 32 codes (16 per codeset) ----
    const f32x4 fz = {0.f, 0.f, 0.f, 0.f};
    float Bb[8], Ss[8];
    #pragma unroll
    for (int i = 0; i < 8; ++i) { Bb[i] = -3.0e38f; Ss[i] = -3.0e38f; }
    unsigned kc8 = (unsigned)cs;             // packed tag = group = t*2+cs

    char* wbase = smem + tid * 16;
    const char* rbase = smem + cs * 8192 + lane * 16;

    for (int t = 0; t < 128; ++t) {
        const int boff = (t & 1) << 14;
        #pragma unroll
        for (int j = 0; j < 4; ++j)          // lane-linear staging
            *(int4*)(wbase + boff + j * 4096) = pf[j];
        __syncthreads();
        if (t < 127) {                       // prefetch tile t+1
            const char* p = pb + (size_t)(t + 1) * 16384;
            #pragma unroll
            for (int j = 0; j < 4; ++j) pf[j] = *(const int4*)(p + j * 4096);
        }
        f32x4 acc[2];
        const char* rb = rbase + boff;
        #pragma unroll
        for (int kd = 0; kd < 4; ++kd) {
            short8 bh = *(const short8*)(rb + kd * 2048);
            short8 bl = *(const short8*)(rb + kd * 2048 + 1024);
            #pragma unroll
            for (int rt = 0; rt < 2; ++rt)
                acc[rt] = __builtin_amdgcn_mfma_f32_16x16x32_bf16(
                    ah[rt][kd], bh, (kd == 0) ? fz : acc[rt], 0, 0, 0);
            #pragma unroll
            for (int rt = 0; rt < 2; ++rt)
                acc[rt] = __builtin_amdgcn_mfma_f32_16x16x32_bf16(
                    ah[rt][kd], bl, acc[rt], 0, 0, 0);
            #pragma unroll
            for (int rt = 0; rt < 2; ++rt)
                acc[rt] = __builtin_amdgcn_mfma_f32_16x16x32_bf16(
                    al[rt][kd], bh, acc[rt], 0, 0, 0);
        }
        // fold: 8-bit group tag in low mantissa; Ss = exact running 2nd-best
        #pragma unroll
        for (int rt = 0; rt < 2; ++rt)
            #pragma unroll
            for (int rg = 0; rg < 4; ++rg) {
                int s = rt * 4 + rg;
                float p = __uint_as_float(
                    (__float_as_uint(acc[rt][rg]) & 0xFFFFFF00u) | kc8);
                Ss[s] = fmaxf(Ss[s], fminf(Bb[s], p));
                Bb[s] = fmaxf(Bb[s], p);
            }
        kc8 += 2;
    }

    // ---- epilogue: merge 16 m16-lanes per slot ----
    float mv1[8], mv2[8]; int mk1[8];
    #pragma unroll
    for (int s = 0; s < 8; ++s) {
        float v1 = Bb[s], v2 = Ss[s];
        int k1 = (int)(((__float_as_uint(v1) & 0xFFu) << 4) | (unsigned)m16);
        #pragma unroll
        for (int off = 1; off < 16; off <<= 1) {
            float ov1 = __shfl_xor(v1, off);
            float ov2 = __shfl_xor(v2, off);
            int   ok1 = __shfl_xor(k1, off);
            bool gt = ov1 > v1, eq = ov1 == v1;
            v2 = gt ? fmaxf(ov2, v1) : fmaxf(v2, ov1);
            v1 = gt ? ov1 : v1;
            k1 = gt ? ok1 : (eq ? min(k1, ok1) : k1);
        }
        mv1[s] = v1; mv2[s] = v2; mk1[s] = k1;
    }
    // cross-codeset merge via LDS: [64 rows][2 cs]
    float* Ev = (float*)smem;                // 512 B
    float* Sv = (float*)(smem + 512);
    int*   Kv = (int*)(smem + 1024);
    float* bsum = (float*)(smem + 1536);
    __syncthreads();
    if (tid == 0) *bsum = 0.f;
    if (m16 == 0) {
        #pragma unroll
        for (int s = 0; s < 8; ++s) {
            int rt = s >> 2, rg = s & 3;
            int row = rs * 32 + rt * 16 + quad * 4 + rg;   // C row = quad*4+reg
            Ev[row * 2 + cs] = mv1[s];
            Sv[row * 2 + cs] = mv2[s];
            Kv[row * 2 + cs] = mk1[s];
        }
    }
    __syncthreads();
    if (tid < 64) {
        float v1 = Ev[tid * 2], v2 = Sv[tid * 2];
        int   k1 = Kv[tid * 2];
        float ov1 = Ev[tid * 2 + 1], ov2 = Sv[tid * 2 + 1];
        int   ok1 = Kv[tid * 2 + 1];
        bool gt = ov1 > v1, eq = ov1 == v1;
        v2 = gt ? fmaxf(ov2, v1) : fmaxf(v2, ov1);
        v1 = gt ? ov1 : v1;
        k1 = gt ? ok1 : (eq ? min(k1, ok1) : k1);
        int n = n0 + tid;
        idx_out[n] = k1;
        atomicAdd(bsum, v1);
        if (v1 - v2 < TAU) {
            int pos = atomicAdd(rcnt, 1);
            if (pos < RCAP) rlist[pos] = n;
        }
    }
    __syncthreads();
    if (tid == 0) atomicAdd(lossacc, *bsum);
}

// ---------------------------------------------------------------------------
// Exact fp32 re-argmax. One block per flagged query; grid-stride.
// ---------------------------------------------------------------------------
__global__ __launch_bounds__(256)
void k_repair(const float* __restrict__ x, const float* __restrict__ invn,
              const float* __restrict__ cbn, int* __restrict__ idx,
              const int* __restrict__ rcnt, const int* __restrict__ rlist) {
    __shared__ float xs[128];
    __shared__ unsigned long long red[4];
    int cnt = *rcnt; if (cnt > RCAP) cnt = RCAP;
    const int tid = threadIdx.x;
    for (int e = blockIdx.x; e < cnt; e += gridDim.x) {
        int n = rlist[e]; int b = n >> 12; int l = n & (Lc - 1);
        __syncthreads();
        if (tid < 128)
            xs[tid] = x[(size_t)b * Dc * Lc + (size_t)tid * Lc + l] * invn[n];
        __syncthreads();
        const float4* xv = (const float4*)xs;
        float best = -3.0e38f; int bk = 0;
        #pragma unroll 1
        for (int i = 0; i < 16; ++i) {
            int k = tid * 16 + i;                 // ascending: '>' keeps min k
            const float4* cr = (const float4*)(cbn + (size_t)k * Dc);
            float s = 0.f;
            #pragma unroll
            for (int j = 0; j < 32; ++j) {
                float4 c = cr[j], xx = xv[j];
                s = fmaf(c.x, xx.x, s); s = fmaf(c.y, xx.y, s);
                s = fmaf(c.z, xx.z, s); s = fmaf(c.w, xx.w, s);
            }
            if (s > best) { best = s; bk = k; }
        }
        unsigned kb = __float_as_uint(best);
        kb = (kb & 0x80000000u) ? ~kb : (kb | 0x80000000u);
        unsigned long long pk =
            ((unsigned long long)kb << 32) | (unsigned)(0xFFFFFFFFu - (unsigned)bk);
        #pragma unroll
        for (int off = 32; off >= 1; off >>= 1) {
            unsigned long long o = __shfl_xor(pk, off);
            pk = (o > pk) ? o : pk;
        }
        if ((tid & 63) == 0) red[tid >> 6] = pk;
        __syncthreads();
        if (tid == 0) {
            unsigned long long m = red[0];
            for (int i = 1; i < 4; ++i) if (red[i] > m) m = red[i];
            idx[n] = (int)(0xFFFFFFFFu - (unsigned)(m & 0xFFFFFFFFull));
        }
    }
}

// ---------------------------------------------------------------------------
// Gather with LDS transpose: coalesced 512B codebook reads, float4 writes.
// Block = 64 l-positions; ot[d][l] staged in LDS.
// ---------------------------------------------------------------------------
__global__ void k_gather(const float* __restrict__ cbn, const int* __restrict__ idx,
                         float* __restrict__ out) {
    __shared__ float ot[128 * 64];   // 32 KB, [d][l]
    __shared__ int sidx[64];
    const int n0 = blockIdx.x << 6;
    const int b  = n0 >> 12;
    const int l0 = n0 & (Lc - 1);
    const int t  = threadIdx.x;
    if (t < 64) sidx[t] = idx[n0 + t];
    __syncthreads();
    {
        int c = t >> 2, sub = t & 3;
        const float* src = cbn + (size_t)sidx[c] * Dc + sub * 32;
        #pragma unroll
        for (int j = 0; j < 8; ++j) {
            float4 v = *(const float4*)(src + j * 4);
            int d = sub * 32 + j * 4;
            ot[(d + 0) * 64 + c] = v.x;
            ot[(d + 1) * 64 + c] = v.y;
            ot[(d + 2) * 64 + c] = v.z;
            ot[(d + 3) * 64 + c] = v.w;
        }
    }
    __syncthreads();
    {
        int dr = t >> 4, lg = (t & 15) * 4;
        float* ob = out + (size_t)b * Dc * Lc + l0 + lg;
        #pragma unroll
        for (int i = 0; i < 8; ++i) {
            int d = dr + i * 16;
            *(float4*)(ob + (size_t)d * Lc) = *(const float4*)&ot[d * 64 + lg];
        }
    }
}

__global__ void k_loss(const float* __restrict__ lacc, float* __restrict__ oloss) {
    *oloss = 2.0f - 2.0f * (*lacc) / (float)Nc;
}

// ---------------------------------------------------------------------------
extern "C" void kernel_launch(void* const* d_in, const int* in_sizes, int n_in,
                              void* d_out, int out_size, void* d_ws, size_t ws_size,
                              hipStream_t stream) {
    const float* x   = (const float*)d_in[0];   // [16][128][4096] fp32
    const float* emb = (const float*)d_in[1];   // [4096][128] fp32
    float* out = (float*)d_out;

    char* ws = (char*)d_ws;
    float* cbn  = (float*)ws;                                  // 2 MB
    char*  blob = ws + (2u << 20);                             // 2 MB
    float* invn = (float*)(ws + (4u << 20));                   // 256 KB
    int*   idx  = (int*)(ws + (4u << 20) + (256u << 10));      // 256 KB
    char*  b5   = ws + (4u << 20) + (512u << 10);
    float* lacc = (float*)b5;
    int*   rcnt = (int*)(b5 + 64);
    int*   rlist= (int*)(b5 + 1024);                           // 128 KB

    k_prep  <<<Kc / 16,  256, 0, stream>>>(emb, cbn, blob, lacc, rcnt);
    k_argmax<<<Nc / 64,  256, 0, stream>>>(x, blob, invn, idx, lacc, rcnt, rlist);
    k_repair<<<1024,     256, 0, stream>>>(x, invn, cbn, idx, rcnt, rlist);
    k_gather<<<Nc / 64,  256, 0, stream>>>(cbn, idx, out);
    k_loss  <<<1, 1,     0, stream>>>(lacc, out + (size_t)Bc * Dc * Lc);
}